// Round 15
// baseline (189.044 us; speedup 1.0000x reference)
//
#include <hip/hip_runtime.h>
#include <hip/hip_cooperative_groups.h>

namespace cg = cooperative_groups;

// GCN, algebraically collapsed + two-sided 256-node bucket partition.
//   y[n]  = dinv[n]*x[n]   (fp16x8, 16B)
//   a[d]  = dinv[d]*(sum_{s->d} y[s] + y[d]);  h1[d] = relu(a[d]@W1 + b1)
//   sdeg[s] = sum_{d: s->d} dinv[d];  c[d] = dinv[d]*sdeg[d] + dinv[d]^2
//   v = sum_d c[d]*h1[d];  g = (1/N)*v@W2 + b2
//   out = concat(g, relu(state@Wm+bm)) @ Wc + bc
// R15 = R12 (best, 132.7us; R13 strips and R14 S-fold both regressed) with
// k_prep+k_sacc FUSED via cooperative grid.sync(): the sorted edge list
// stays in LDS across the sync (kills the 10MB sortD write+read + eoffsG
// + one launch). Phase A publishes dinv/yh globally; agent-scope fences in
// grid.sync() handle cross-XCD L2 writeback/invalidate.

#define NPB   256      // nodes per bucket
#define CAP   4096     // edge capacity per bucket (mean 3200, +15.8 sigma)
#define MAXB  512      // max buckets (N <= 131072)
#define PCH   6144     // edges per partition block
#define PTH   512      // partition block threads
#define PK    (PCH/PTH) // 12 edges per thread

typedef unsigned uv4 __attribute__((ext_vector_type(4)));
typedef _Float16 half8 __attribute__((ext_vector_type(8)));

// Block-level radix scatter, ONE side per block (blockIdx.y: 0=dst, 1=src).
// Payload u32: low 17 bits = other-endpoint id, bits [24:17] = own low-8.
__launch_bounds__(PTH)
__global__ void k_part(const int* __restrict__ src, const int* __restrict__ dst,
                       int E,
                       unsigned* __restrict__ curD, unsigned* __restrict__ curS,
                       unsigned* __restrict__ bufD, unsigned* __restrict__ bufS) {
    __shared__ unsigned       stage[PCH];   // 24 KB
    __shared__ unsigned short bkt[PCH];     // 12 KB
    __shared__ unsigned lc[MAXB], lofs[MAXB], gb[MAXB], sc[MAXB]; // 8 KB
    int t = threadIdx.x;
    int side = blockIdx.y;
    int base = blockIdx.x * PCH;
    int cnt = min(PCH, E - base);

    unsigned ss[PK], dd[PK];
#pragma unroll
    for (int k = 0; k < PK; ++k) {
        int e = base + k * PTH + t;
        if (e < E) { ss[k] = (unsigned)src[e]; dd[k] = (unsigned)dst[e]; }
        else ss[k] = 0xffffffffu;
    }

    lc[t] = 0;                       // PTH == MAXB
    __syncthreads();

    unsigned br[PK];
#pragma unroll
    for (int k = 0; k < PK; ++k) {
        if (ss[k] == 0xffffffffu) { br[k] = 0xffffffffu; continue; }
        unsigned key = side ? ss[k] : dd[k];
        unsigned b = key >> 8;
        unsigned r = atomicAdd(&lc[b], 1u);
        br[k] = (b << 16) | r;
    }
    __syncthreads();

    // exclusive scan of lc[0..MAXB), 1/thread (Hillis-Steele)
    unsigned v = lc[t];
    sc[t] = v;
    __syncthreads();
    for (int o = 1; o < MAXB; o <<= 1) {
        unsigned add = (t >= o) ? sc[t - o] : 0u;
        __syncthreads();
        sc[t] += add;
        __syncthreads();
    }
    lofs[t] = sc[t] - v;
    gb[t] = v ? atomicAdd(side ? &curS[t] : &curD[t], v) : 0u;
    __syncthreads();

    // stage bucket-ordered
#pragma unroll
    for (int k = 0; k < PK; ++k) {
        if (br[k] == 0xffffffffu) continue;
        unsigned b = br[k] >> 16, r = br[k] & 0xffffu;
        unsigned pos = lofs[b] + r;
        stage[pos] = side ? (dd[k] | ((ss[k] & 255u) << 17))
                          : (ss[k] | ((dd[k] & 255u) << 17));
        bkt[pos] = (unsigned short)b;
    }
    __syncthreads();

    // contiguous-run writeout (runs avg ~15.7 words)
    unsigned* obuf = side ? bufS : bufD;
    for (int i = t; i < cnt; i += PTH) {
        unsigned b = bkt[i];
        obuf[(size_t)b * CAP + gb[b] + ((unsigned)i - lofs[b])] = stage[i];
    }
}

// Fused prep+accumulate (cooperative, one block per bucket):
// Phase A: hist (1 LDS atomic/edge) -> scan -> counting sort IN LDS;
//          publish dinv[n], yh[n]=fp16(dinv*x) globally.
// grid.sync()  (all yh/dinv visible device-wide)
// Phase B: S side = sdeg via LDS float atomics over bufS (dinv gathers);
//          D side = per-node segment walk over the LDS-resident sorted list
//          (yh gathers); node math; butterfly reduce-scatter; vsum atomics.
__launch_bounds__(NPB)
__global__ void k_fused(const unsigned* __restrict__ bufD, const unsigned* __restrict__ cntD,
                        const unsigned* __restrict__ bufS, const unsigned* __restrict__ cntS,
                        const float* __restrict__ x, int N,
                        float* __restrict__ dinv, half8* __restrict__ yh,
                        const float* __restrict__ W1, const float* __restrict__ b1,
                        float* __restrict__ vsum) {
    __shared__ unsigned sorted[CAP];    // 16 KB, persists across grid.sync
    __shared__ unsigned degl[NPB], scs[NPB], eoffs[NPB];
    __shared__ float sl[NPB];
    __shared__ float W1s[512];
    __shared__ float b1s[64];
    __shared__ float red[4][64];
    int t = threadIdx.x, b = blockIdx.x;
    W1s[t] = W1[t];
    W1s[t + 256] = W1[t + 256];
    if (t < 64) b1s[t] = b1[t];
    degl[t] = 0u;
    sl[t] = 0.f;
    __syncthreads();

    // ---- Phase A ----
    unsigned cnt = cntD[b];
    const uv4* eb = (const uv4*)(bufD + (size_t)b * CAP);
    uv4 w[4];
    unsigned short rk[16];
#pragma unroll
    for (int r = 0; r < 4; ++r) {
        unsigned base = ((unsigned)t + (unsigned)r * NPB) * 4u;
        if (base < cnt) {
            w[r] = eb[t + r * NPB];
            unsigned nv = min(cnt - base, 4u);
#pragma unroll
            for (unsigned k = 0; k < 4; ++k)
                if (k < nv)
                    rk[r * 4 + k] = (unsigned short)atomicAdd(&degl[w[r][k] >> 17], 1u);
        }
    }
    __syncthreads();

    // exclusive scan of degl (256 bins, 256 threads)
    unsigned hv = degl[t];
    scs[t] = hv;
    __syncthreads();
    for (int o = 1; o < NPB; o <<= 1) {
        unsigned add = (t >= o) ? scs[t - o] : 0u;
        __syncthreads();
        scs[t] += add;
        __syncthreads();
    }
    eoffs[t] = scs[t] - hv;
    __syncthreads();

    // place into sorted order (plain LDS writes)
#pragma unroll
    for (int r = 0; r < 4; ++r) {
        unsigned base = ((unsigned)t + (unsigned)r * NPB) * 4u;
        if (base < cnt) {
            unsigned nv = min(cnt - base, 4u);
#pragma unroll
            for (unsigned k = 0; k < 4; ++k)
                if (k < nv)
                    sorted[eoffs[w[r][k] >> 17] + rk[r * 4 + k]] = w[r][k];
        }
    }

    // publish dinv + fp16-packed y
    int n = b * NPB + t;
    float di = rsqrtf((float)(hv + 1u));
    if (n < N) {
        dinv[n] = di;
        float4 u0 = ((const float4*)(x + (size_t)n * 8))[0];
        float4 u1 = ((const float4*)(x + (size_t)n * 8))[1];
        half8 h;
        h[0] = (_Float16)(di * u0.x); h[1] = (_Float16)(di * u0.y);
        h[2] = (_Float16)(di * u0.z); h[3] = (_Float16)(di * u0.w);
        h[4] = (_Float16)(di * u1.x); h[5] = (_Float16)(di * u1.y);
        h[6] = (_Float16)(di * u1.z); h[7] = (_Float16)(di * u1.w);
        yh[n] = h;
    }

    cg::this_grid().sync();   // yh/dinv complete device-wide; sorted[] kept in LDS

    // ---- Phase B ----
    // S side: sdeg (LDS float atomic 1/edge, batched-4 dinv gathers)
    {
        unsigned cntS_b = cntS[b];
        const uv4* es = (const uv4*)(bufS + (size_t)b * CAP);
#pragma unroll
        for (int r = 0; r < 4; ++r) {
            unsigned base = ((unsigned)t + (unsigned)r * NPB) * 4u;
            if (base < cntS_b) {
                uv4 ws = es[t + r * NPB];
                unsigned nv = min(cntS_b - base, 4u);
                float dv[4];
#pragma unroll
                for (unsigned k = 0; k < 4; ++k)
                    dv[k] = (k < nv) ? dinv[ws[k] & 0x1ffffu] : 0.f;
#pragma unroll
                for (unsigned k = 0; k < 4; ++k)
                    if (k < nv) atomicAdd(&sl[ws[k] >> 17], dv[k]);
            }
        }
    }

    // D side: per-node segment walk over LDS-resident sorted list
    unsigned e0 = eoffs[t], deg = hv;
    float a[8] = {0.f, 0.f, 0.f, 0.f, 0.f, 0.f, 0.f, 0.f};
    unsigned i = 0;
    for (; i + 4 <= deg; i += 4) {
        unsigned s0 = sorted[e0 + i]     & 0x1ffffu;
        unsigned s1 = sorted[e0 + i + 1] & 0x1ffffu;
        unsigned s2 = sorted[e0 + i + 2] & 0x1ffffu;
        unsigned s3 = sorted[e0 + i + 3] & 0x1ffffu;
        half8 g0 = yh[s0], g1 = yh[s1], g2 = yh[s2], g3 = yh[s3];
#pragma unroll
        for (int j = 0; j < 8; ++j)
            a[j] += ((float)g0[j] + (float)g1[j]) + ((float)g2[j] + (float)g3[j]);
    }
    for (; i < deg; ++i) {
        half8 g = yh[sorted[e0 + i] & 0x1ffffu];
#pragma unroll
        for (int j = 0; j < 8; ++j) a[j] += (float)g[j];
    }
    __syncthreads();   // sl complete before node math reads it

    float c = 0.f;
    if (n < N) {
        half8 hs = yh[n];
#pragma unroll
        for (int j = 0; j < 8; ++j) a[j] = di * (a[j] + (float)hs[j]);
        c = fmaf(di, sl[t], di * di);
    } else {
#pragma unroll
        for (int j = 0; j < 8; ++j) a[j] = 0.f;
    }

    float vv[64];
#pragma unroll
    for (int k = 0; k < 64; ++k) {
        float h = b1s[k];
#pragma unroll
        for (int j = 0; j < 8; ++j) h = fmaf(a[j], W1s[j * 64 + k], h);
        vv[k] = c * fmaxf(h, 0.f);
    }

    // Butterfly reduce-scatter (validated R2-R14): lane l ends with wave-sum
    // of component l in vv[0].
    int lane = t & 63;
#pragma unroll
    for (int half = 32; half >= 1; half >>= 1) {
        bool upper = (lane & half) != 0;
#pragma unroll
        for (int i2 = 0; i2 < 32; ++i2) {
            if (i2 >= half) break;
            float lo = vv[i2];
            float hi = vv[i2 + half];
            float give = upper ? lo : hi;
            float keep = upper ? hi : lo;
            float recv = __shfl_xor(give, half);
            vv[i2] = keep + recv;
        }
    }
    red[t >> 6][lane] = vv[0];
    __syncthreads();
    if (t < 64)
        unsafeAtomicAdd(&vsum[t], red[0][t] + red[1][t] + red[2][t] + red[3][t]);
}

// Single block, 64 threads: g = (1/N)*vsum@W2+b2, s = relu(state@Wm+bm),
// out = [g,s]@Wc+bc.
__global__ void k_final(const float* __restrict__ vsum,
                        const float* __restrict__ W2, const float* __restrict__ b2,
                        const float* __restrict__ state, const float* __restrict__ Wm,
                        const float* __restrict__ bm, const float* __restrict__ Wc,
                        const float* __restrict__ bc, float* __restrict__ out,
                        float inv_n) {
    __shared__ float v[64];
    __shared__ float gs[128];
    int k = threadIdx.x;   // blockDim = 64

    v[k] = vsum[k];
    __syncthreads();

    float g = 0.f;
    for (int j = 0; j < 64; ++j) g = fmaf(v[j], W2[j * 64 + k], g);
    g = fmaf(g, inv_n, b2[k]);

    float s = bm[k];
    for (int j = 0; j < 8; ++j) s = fmaf(state[j], Wm[j * 64 + k], s);
    s = fmaxf(s, 0.f);

    gs[k] = g;
    gs[64 + k] = s;
    __syncthreads();

    if (k < 2) {
        float o = bc[k];
        for (int j = 0; j < 128; ++j) o = fmaf(gs[j], Wc[j * 2 + k], o);
        out[k] = o;
    }
}

extern "C" void kernel_launch(void* const* d_in, const int* in_sizes, int n_in,
                              void* d_out, int out_size, void* d_ws, size_t ws_size,
                              hipStream_t stream) {
    const float* x     = (const float*)d_in[0];
    const float* state = (const float*)d_in[1];
    const float* W1    = (const float*)d_in[2];
    const float* b1    = (const float*)d_in[3];
    const float* W2    = (const float*)d_in[4];
    const float* b2    = (const float*)d_in[5];
    const float* Wm    = (const float*)d_in[6];
    const float* bm    = (const float*)d_in[7];
    const float* Wc    = (const float*)d_in[8];
    const float* bc    = (const float*)d_in[9];
    const int*   ei    = (const int*)d_in[10];

    const int N = in_sizes[0] / 8;
    const int E = in_sizes[10] / 2;
    const int* src = ei;
    const int* dst = ei + E;
    const int nbuck = (N + NPB - 1) / NPB;   // 391 for N=100000

    char* ws = (char*)d_ws;
    size_t off = 0;
    auto alloc = [&](size_t bytes) -> void* {
        void* p = ws + off;
        off += (bytes + 255) & ~(size_t)255;
        return p;
    };
    // Zeroed region: cursors + vsum (~4.4 KB).
    unsigned* curD = (unsigned*)alloc((size_t)MAXB * 4);
    unsigned* curS = (unsigned*)alloc((size_t)MAXB * 4);
    float*    vsum = (float*)   alloc(64 * 4);
    size_t zero_bytes = off;
    // No-init region.
    unsigned* bufD = (unsigned*)alloc((size_t)nbuck * CAP * 4);
    unsigned* bufS = (unsigned*)alloc((size_t)nbuck * CAP * 4);
    float*    dinv = (float*)   alloc((size_t)N * 4);
    half8*    yh   = (half8*)   alloc((size_t)N * 16);
    (void)ws_size; (void)n_in; (void)out_size;

    hipMemsetAsync(d_ws, 0, zero_bytes, stream);

    dim3 pgrid((E + PCH - 1) / PCH, 2);
    k_part<<<pgrid, PTH, 0, stream>>>(src, dst, E, curD, curS, bufD, bufS);

    int Nv = N;
    void* args[] = { (void*)&bufD, (void*)&curD, (void*)&bufS, (void*)&curS,
                     (void*)&x, (void*)&Nv, (void*)&dinv, (void*)&yh,
                     (void*)&W1, (void*)&b1, (void*)&vsum };
    hipLaunchCooperativeKernel((const void*)k_fused, dim3(nbuck), dim3(NPB),
                               args, 0, stream);

    k_final<<<1, 64, 0, stream>>>(vsum, W2, b2, state, Wm, bm, Wc, bc,
                                  (float*)d_out, 1.0f / (float)N);
}

// Round 16
// 132.274 us; speedup vs baseline: 1.4292x; 1.4292x over previous
//
#include <hip/hip_runtime.h>

// GCN, algebraically collapsed + two-sided 256-node bucket partition.
//   y[n]  = dinv[n]*x[n]   (fp16x8, 16B)
//   a[d]  = dinv[d]*(sum_{s->d} y[s] + y[d]);  h1[d] = relu(a[d]@W1 + b1)
//   sdeg[s] = sum_{d: s->d} dinv[d];  c[d] = dinv[d]*sdeg[d] + dinv[d]^2
//   v = sum_d c[d]*h1[d];  g = (1/N)*v@W2 + b2
//   out = concat(g, relu(state@Wm+bm)) @ Wc + bc
// R16 = exact revert to R12 (best measured: 132.7us). Refinements falsified
// on this structure: R13 balanced strips (+1.7), R14 value-carrying S-fold
// (+7.5), R15 cooperative prep+sacc fusion (+56). Session law: streaming
// bytes are ~free; divergent/LDS-RMW ops at ~25-30ns each are the currency.
// R12's ~5M such ops => ~130us distributed floor; counters agree (all pipes
// <10% busy, no single >=10us item remains).

#define NPB   256      // nodes per bucket
#define CAP   4096     // edge capacity per bucket (mean 3200, +15.8 sigma)
#define MAXB  512      // max buckets (N <= 131072)
#define PCH   6144     // edges per partition block
#define PTH   512      // partition block threads
#define PK    (PCH/PTH) // 12 edges per thread

typedef unsigned uv4 __attribute__((ext_vector_type(4)));
typedef _Float16 half8 __attribute__((ext_vector_type(8)));

// Block-level radix scatter, ONE side per block (blockIdx.y: 0=dst, 1=src).
// Payload u32: low 17 bits = other-endpoint id, bits [24:17] = own low-8.
__launch_bounds__(PTH)
__global__ void k_part(const int* __restrict__ src, const int* __restrict__ dst,
                       int E,
                       unsigned* __restrict__ curD, unsigned* __restrict__ curS,
                       unsigned* __restrict__ bufD, unsigned* __restrict__ bufS) {
    __shared__ unsigned       stage[PCH];   // 24 KB
    __shared__ unsigned short bkt[PCH];     // 12 KB
    __shared__ unsigned lc[MAXB], lofs[MAXB], gb[MAXB], sc[MAXB]; // 8 KB
    int t = threadIdx.x;
    int side = blockIdx.y;
    int base = blockIdx.x * PCH;
    int cnt = min(PCH, E - base);

    unsigned ss[PK], dd[PK];
#pragma unroll
    for (int k = 0; k < PK; ++k) {
        int e = base + k * PTH + t;
        if (e < E) { ss[k] = (unsigned)src[e]; dd[k] = (unsigned)dst[e]; }
        else ss[k] = 0xffffffffu;
    }

    lc[t] = 0;                       // PTH == MAXB
    __syncthreads();

    unsigned br[PK];
#pragma unroll
    for (int k = 0; k < PK; ++k) {
        if (ss[k] == 0xffffffffu) { br[k] = 0xffffffffu; continue; }
        unsigned key = side ? ss[k] : dd[k];
        unsigned b = key >> 8;
        unsigned r = atomicAdd(&lc[b], 1u);
        br[k] = (b << 16) | r;
    }
    __syncthreads();

    // exclusive scan of lc[0..MAXB), 1/thread (Hillis-Steele)
    unsigned v = lc[t];
    sc[t] = v;
    __syncthreads();
    for (int o = 1; o < MAXB; o <<= 1) {
        unsigned add = (t >= o) ? sc[t - o] : 0u;
        __syncthreads();
        sc[t] += add;
        __syncthreads();
    }
    lofs[t] = sc[t] - v;
    gb[t] = v ? atomicAdd(side ? &curS[t] : &curD[t], v) : 0u;
    __syncthreads();

    // stage bucket-ordered
#pragma unroll
    for (int k = 0; k < PK; ++k) {
        if (br[k] == 0xffffffffu) continue;
        unsigned b = br[k] >> 16, r = br[k] & 0xffffu;
        unsigned pos = lofs[b] + r;
        stage[pos] = side ? (dd[k] | ((ss[k] & 255u) << 17))
                          : (ss[k] | ((dd[k] & 255u) << 17));
        bkt[pos] = (unsigned short)b;
    }
    __syncthreads();

    // contiguous-run writeout (runs avg ~15.7 words)
    unsigned* obuf = side ? bufS : bufD;
    for (int i = t; i < cnt; i += PTH) {
        unsigned b = bkt[i];
        obuf[(size_t)b * CAP + gb[b] + ((unsigned)i - lofs[b])] = stage[i];
    }
}

// Per dst-bucket: hist (1 LDS atomic/edge) -> counting sort persisted to
// sortD + eoffsG (coalesced); dinv + yh = fp16(dinv*x). NO global atomics.
__launch_bounds__(NPB)
__global__ void k_prep(const unsigned* __restrict__ bufD, const unsigned* __restrict__ cntD,
                       const float* __restrict__ x, int N,
                       float* __restrict__ dinv, half8* __restrict__ yh,
                       unsigned* __restrict__ sortD, unsigned* __restrict__ eoffsG) {
    __shared__ unsigned sorted[CAP];    // 16 KB
    __shared__ unsigned degl[NPB], scs[NPB], eoffs[NPB];
    int t = threadIdx.x, b = blockIdx.x;
    degl[t] = 0u;
    __syncthreads();

    unsigned cnt = cntD[b];
    const uv4* eb = (const uv4*)(bufD + (size_t)b * CAP);
    uv4 w[4];
    unsigned short rk[16];
#pragma unroll
    for (int r = 0; r < 4; ++r) {
        unsigned base = ((unsigned)t + (unsigned)r * NPB) * 4u;
        if (base < cnt) {
            w[r] = eb[t + r * NPB];
            unsigned nv = min(cnt - base, 4u);
#pragma unroll
            for (unsigned k = 0; k < 4; ++k)
                if (k < nv)
                    rk[r * 4 + k] = (unsigned short)atomicAdd(&degl[w[r][k] >> 17], 1u);
        }
    }
    __syncthreads();

    // exclusive scan of degl (256 bins, 256 threads)
    unsigned hv = degl[t];
    scs[t] = hv;
    __syncthreads();
    for (int o = 1; o < NPB; o <<= 1) {
        unsigned add = (t >= o) ? scs[t - o] : 0u;
        __syncthreads();
        scs[t] += add;
        __syncthreads();
    }
    eoffs[t] = scs[t] - hv;
    __syncthreads();

    // place into sorted order (plain LDS writes)
#pragma unroll
    for (int r = 0; r < 4; ++r) {
        unsigned base = ((unsigned)t + (unsigned)r * NPB) * 4u;
        if (base < cnt) {
            unsigned nv = min(cnt - base, 4u);
#pragma unroll
            for (unsigned k = 0; k < 4; ++k)
                if (k < nv)
                    sorted[eoffs[w[r][k] >> 17] + rk[r * 4 + k]] = w[r][k];
        }
    }
    __syncthreads();

    // persist sort (coalesced; trailing garbage beyond cnt never read)
    uv4* so = (uv4*)(sortD + (size_t)b * CAP);
    const uv4* slv = (const uv4*)sorted;
#pragma unroll
    for (int r = 0; r < 4; ++r) so[t + r * NPB] = slv[t + r * NPB];
    eoffsG[(size_t)b * NPB + t] = eoffs[t];

    int n = b * NPB + t;
    if (n < N) {
        float di = rsqrtf((float)(degl[t] + 1u));
        dinv[n] = di;
        float4 u0 = ((const float4*)(x + (size_t)n * 8))[0];
        float4 u1 = ((const float4*)(x + (size_t)n * 8))[1];
        half8 h;
        h[0] = (_Float16)(di * u0.x); h[1] = (_Float16)(di * u0.y);
        h[2] = (_Float16)(di * u0.z); h[3] = (_Float16)(di * u0.w);
        h[4] = (_Float16)(di * u1.x); h[5] = (_Float16)(di * u1.y);
        h[6] = (_Float16)(di * u1.z); h[7] = (_Float16)(di * u1.w);
        yh[n] = h;
    }
}

// Per bucket b: sdeg via LDS float atomics over bufS (1/edge); D side reads
// each node's sorted segment DIRECTLY from global (contiguous,
// single-consumer), segmented register reduce, fused node math, butterfly
// reduce-scatter, fold into vsum[64].
__launch_bounds__(NPB)
__global__ void k_sacc(const unsigned* __restrict__ sortD, const unsigned* __restrict__ cntD,
                       const unsigned* __restrict__ eoffsG,
                       const unsigned* __restrict__ bufS, const unsigned* __restrict__ cntS,
                       const half8* __restrict__ yh, const float* __restrict__ dinv,
                       const float* __restrict__ W1, const float* __restrict__ b1,
                       float* __restrict__ vsum, int N) {
    __shared__ unsigned eo[NPB + 1];
    __shared__ float sl[NPB];
    __shared__ float W1s[512];
    __shared__ float b1s[64];
    __shared__ float red[4][64];
    int t = threadIdx.x, b = blockIdx.x;
    W1s[t] = W1[t];
    W1s[t + 256] = W1[t + 256];
    if (t < 64) b1s[t] = b1[t];
    sl[t] = 0.f;
    eo[t] = eoffsG[(size_t)b * NPB + t];
    if (t == 0) eo[NPB] = cntD[b];
    __syncthreads();

    // S side: sdeg (LDS float atomic 1/edge, batched-4 dinv gathers)
    {
        unsigned cnt = cntS[b];
        const uv4* eb = (const uv4*)(bufS + (size_t)b * CAP);
#pragma unroll
        for (int r = 0; r < 4; ++r) {
            unsigned base = ((unsigned)t + (unsigned)r * NPB) * 4u;
            if (base < cnt) {
                uv4 w = eb[t + r * NPB];
                unsigned nv = min(cnt - base, 4u);
                float dv[4];
#pragma unroll
                for (unsigned k = 0; k < 4; ++k)
                    dv[k] = (k < nv) ? dinv[w[k] & 0x1ffffu] : 0.f;
#pragma unroll
                for (unsigned k = 0; k < 4; ++k)
                    if (k < nv) atomicAdd(&sl[w[k] >> 17], dv[k]);
            }
        }
    }

    // D side: direct-global segmented gather-reduce, thread t owns node t
    unsigned e0 = eo[t], deg = eo[t + 1] - e0;
    const unsigned* seg = sortD + (size_t)b * CAP + e0;
    float a[8] = {0.f, 0.f, 0.f, 0.f, 0.f, 0.f, 0.f, 0.f};
    unsigned i = 0;
    for (; i + 4 <= deg; i += 4) {
        unsigned s0 = seg[i]     & 0x1ffffu;
        unsigned s1 = seg[i + 1] & 0x1ffffu;
        unsigned s2 = seg[i + 2] & 0x1ffffu;
        unsigned s3 = seg[i + 3] & 0x1ffffu;
        half8 g0 = yh[s0], g1 = yh[s1], g2 = yh[s2], g3 = yh[s3];
#pragma unroll
        for (int j = 0; j < 8; ++j)
            a[j] += ((float)g0[j] + (float)g1[j]) + ((float)g2[j] + (float)g3[j]);
    }
    for (; i < deg; ++i) {
        half8 g = yh[seg[i] & 0x1ffffu];
#pragma unroll
        for (int j = 0; j < 8; ++j) a[j] += (float)g[j];
    }
    __syncthreads();   // sl complete before node math reads it

    int n = b * NPB + t;
    float c = 0.f;
    if (n < N) {
        float di = rsqrtf((float)(deg + 1u));
        half8 hs = yh[n];
#pragma unroll
        for (int j = 0; j < 8; ++j) a[j] = di * (a[j] + (float)hs[j]);
        c = fmaf(di, sl[t], di * di);
    } else {
#pragma unroll
        for (int j = 0; j < 8; ++j) a[j] = 0.f;
    }

    float vv[64];
#pragma unroll
    for (int k = 0; k < 64; ++k) {
        float h = b1s[k];
#pragma unroll
        for (int j = 0; j < 8; ++j) h = fmaf(a[j], W1s[j * 64 + k], h);
        vv[k] = c * fmaxf(h, 0.f);
    }

    // Butterfly reduce-scatter (validated R2-R15): lane l ends with wave-sum
    // of component l in vv[0].
    int lane = t & 63;
#pragma unroll
    for (int half = 32; half >= 1; half >>= 1) {
        bool upper = (lane & half) != 0;
#pragma unroll
        for (int i2 = 0; i2 < 32; ++i2) {
            if (i2 >= half) break;
            float lo = vv[i2];
            float hi = vv[i2 + half];
            float give = upper ? lo : hi;
            float keep = upper ? hi : lo;
            float recv = __shfl_xor(give, half);
            vv[i2] = keep + recv;
        }
    }
    red[t >> 6][lane] = vv[0];
    __syncthreads();
    if (t < 64)
        unsafeAtomicAdd(&vsum[t], red[0][t] + red[1][t] + red[2][t] + red[3][t]);
}

// Single block, 64 threads: g = (1/N)*vsum@W2+b2, s = relu(state@Wm+bm),
// out = [g,s]@Wc+bc.
__global__ void k_final(const float* __restrict__ vsum,
                        const float* __restrict__ W2, const float* __restrict__ b2,
                        const float* __restrict__ state, const float* __restrict__ Wm,
                        const float* __restrict__ bm, const float* __restrict__ Wc,
                        const float* __restrict__ bc, float* __restrict__ out,
                        float inv_n) {
    __shared__ float v[64];
    __shared__ float gs[128];
    int k = threadIdx.x;   // blockDim = 64

    v[k] = vsum[k];
    __syncthreads();

    float g = 0.f;
    for (int j = 0; j < 64; ++j) g = fmaf(v[j], W2[j * 64 + k], g);
    g = fmaf(g, inv_n, b2[k]);

    float s = bm[k];
    for (int j = 0; j < 8; ++j) s = fmaf(state[j], Wm[j * 64 + k], s);
    s = fmaxf(s, 0.f);

    gs[k] = g;
    gs[64 + k] = s;
    __syncthreads();

    if (k < 2) {
        float o = bc[k];
        for (int j = 0; j < 128; ++j) o = fmaf(gs[j], Wc[j * 2 + k], o);
        out[k] = o;
    }
}

extern "C" void kernel_launch(void* const* d_in, const int* in_sizes, int n_in,
                              void* d_out, int out_size, void* d_ws, size_t ws_size,
                              hipStream_t stream) {
    const float* x     = (const float*)d_in[0];
    const float* state = (const float*)d_in[1];
    const float* W1    = (const float*)d_in[2];
    const float* b1    = (const float*)d_in[3];
    const float* W2    = (const float*)d_in[4];
    const float* b2    = (const float*)d_in[5];
    const float* Wm    = (const float*)d_in[6];
    const float* bm    = (const float*)d_in[7];
    const float* Wc    = (const float*)d_in[8];
    const float* bc    = (const float*)d_in[9];
    const int*   ei    = (const int*)d_in[10];

    const int N = in_sizes[0] / 8;
    const int E = in_sizes[10] / 2;
    const int* src = ei;
    const int* dst = ei + E;
    const int nbuck = (N + NPB - 1) / NPB;   // 391 for N=100000

    char* ws = (char*)d_ws;
    size_t off = 0;
    auto alloc = [&](size_t bytes) -> void* {
        void* p = ws + off;
        off += (bytes + 255) & ~(size_t)255;
        return p;
    };
    // Zeroed region: cursors + vsum (~4.4 KB).
    unsigned* curD = (unsigned*)alloc((size_t)MAXB * 4);
    unsigned* curS = (unsigned*)alloc((size_t)MAXB * 4);
    float*    vsum = (float*)   alloc(64 * 4);
    size_t zero_bytes = off;
    // No-init region.
    unsigned* bufD   = (unsigned*)alloc((size_t)nbuck * CAP * 4);
    unsigned* bufS   = (unsigned*)alloc((size_t)nbuck * CAP * 4);
    unsigned* sortD  = (unsigned*)alloc((size_t)nbuck * CAP * 4);
    unsigned* eoffsG = (unsigned*)alloc((size_t)nbuck * NPB * 4);
    float*    dinv   = (float*)   alloc((size_t)N * 4);
    half8*    yh     = (half8*)   alloc((size_t)N * 16);
    (void)ws_size; (void)n_in; (void)out_size;

    hipMemsetAsync(d_ws, 0, zero_bytes, stream);

    dim3 pgrid((E + PCH - 1) / PCH, 2);
    k_part<<<pgrid, PTH, 0, stream>>>(src, dst, E, curD, curS, bufD, bufS);
    k_prep<<<nbuck, NPB, 0, stream>>>(bufD, curD, x, N, dinv, yh, sortD, eoffsG);
    k_sacc<<<nbuck, NPB, 0, stream>>>(sortD, curD, eoffsG, bufS, curS, yh, dinv,
                                      W1, b1, vsum, N);
    k_final<<<1, 64, 0, stream>>>(vsum, W2, b2, state, Wm, bm, Wc, bc,
                                  (float*)d_out, 1.0f / (float)N);
}